// Round 6
// baseline (127.950 us; speedup 1.0000x reference)
//
#include <hip/hip_runtime.h>
#include <stdint.h>
#include <stddef.h>

// Problem constants (reference: M=16, K=8192, N=8192, GROUP=128)
#define MM 16
#define KK 8192
#define NN 8192
#define GROUP_SZ 128
#define NGROUP 64
#define KPACK 1024           // K/8 packed int32 per output row
#define NT 128               // 64-col n-tiles
#define KQN 8                // k-split factor
#define KSL (KK / KQN)       // 1024 k per block
#define GPB (KSL / GROUP_SZ) // 8 groups per block
#define CPB 64               // n-cols per block

typedef _Float16 half8_t __attribute__((ext_vector_type(8)));
typedef _Float16 half2_t __attribute__((ext_vector_type(2)));
typedef float float4_t __attribute__((ext_vector_type(4)));
typedef uint32_t uint4_t __attribute__((ext_vector_type(4)));

// XOR swizzle on 16B-chunk index within a 256-chunk x-stage buffer.
// Validated in rounds 3-5 (write & read beats both <=2-way, free).
__device__ __forceinline__ int swz(int fc) {
    return fc ^ (((fc >> 3) ^ (fc >> 6)) & 7);
}

// out[m][n] = bias[n]  (split-k partials atomicAdd on top; re-run per iter)
__global__ __launch_bounds__(256) void wq_init(const float* __restrict__ bias,
                                               float* __restrict__ out) {
    const int idx = (blockIdx.x * 256 + threadIdx.x) * 4;
    const int m  = idx >> 13;          // NN = 2^13
    const int nn = idx & (NN - 1);
    *(float4_t*)(out + (size_t)m * NN + nn) = *(const float4_t*)(bias + nn);
}

// ---------------------------------------------------------------------------
// 1024 blocks = 128 n-tiles x 8 k-splits; 256 threads (4 waves).
// Block (nt, kq): cols [nt*64, +64), k [kq*1024, +1024) = 8 groups.
//
// qweight: cooperatively streamed into LDS as CONTIGUOUS 512B runs
//   (8 sequential 64B lines per run) -- vs the previous 64B-granule gather
//   at 4KB stride that pinned rounds 0/3/4/5 at ~20us of HBM scatter.
//   LDS layout row-slice-major with per-row XOR swizzle (conflict-free).
// x: staged once per block (shared by all 4 waves) in the validated
//   fragment-ordered swizzled layout, double-buffered, 1 barrier/group.
// Each wave computes one 16-col MFMA tile over the 8 groups; per-group math
// (rte f16 cvt, fdot2 exact zero-point sums, f32 accumulators, deferred
// epilogue shuffles) is identical to the validated round-3/4/5 kernels.
// Split-k: partials atomicAdd'ed onto bias-initialized out.
// LDS 40KB -> 4 blocks/CU (16 waves/CU).
// ---------------------------------------------------------------------------
__global__ __launch_bounds__(256, 4) void wq_main(
        const float* __restrict__ x,
        const int* __restrict__ qweight,
        const float* __restrict__ scales,
        const float* __restrict__ zeros,
        float* __restrict__ out) {
    __shared__ alignas(16) int      qlds[CPB * 128];     // 32 KB (64 rows x 512B)
    __shared__ alignas(16) _Float16 xstage[2 * 2048];    // 8 KB (2 x 4KB bufs)

    const int t    = threadIdx.x;
    const int bid  = blockIdx.x;
    const int nt   = bid & (NT - 1);   // consecutive bids -> different XCDs;
    const int kq   = bid >> 7;         // same-nt pair is 128 apart -> same XCD
    const int w    = t >> 6;
    const int lane = t & 63;
    const int nlo  = lane & 15;
    const int quad = lane >> 4;
    const int n    = nt * CPB + w * 16 + nlo;

    // ---- cooperative qweight stream: 2048 chunks of 16B; chunk c ----
    // rr = c>>5 (row 0..63), b = c&31 (16B piece within 512B row-slice).
    // Per 64-lane wave instr: two full 512B contiguous runs.
    uint4_t qv[8];
    #pragma unroll
    for (int i = 0; i < 8; ++i) {
        const int c  = i * 256 + t;
        const int rr = c >> 5, b = c & 31;
        qv[i] = *(const uint4_t*)(qweight + (size_t)(nt * CPB + rr) * KPACK
                                  + kq * (KSL / 8) + b * 4);
    }

    // ---- x group-0 load (thread t -> row xr, k-oct xo) ----
    const int xr = t >> 4, xo = t & 15;
    const float* xbase = x + (size_t)xr * KK + kq * KSL + xo * 8;
    float4_t pxa = *(const float4_t*)(xbase);
    float4_t pxb = *(const float4_t*)(xbase + 4);

    // ---- hoisted per-group scale / zero-correction coefficients ----
    float sA[GPB], cA[GPB];
    #pragma unroll
    for (int g = 0; g < GPB; ++g) {
        const size_t ro = (size_t)(kq * GPB + g) * NN + n;
        const float sg = scales[ro];
        const float zg = zeros[ro];
        sA[g] = sg;
        cA[g] = zg - 1024.0f * sg;
    }

    // ---- qlds write: row-slice-major, per-row XOR swizzle ----
    // store (rr, b) at chunk rr*32 + (b ^ (rr&7))  [writer beats 2-way max]
    #pragma unroll
    for (int i = 0; i < 8; ++i) {
        const int c  = i * 256 + t;
        const int rr = c >> 5, b = c & 31;
        *(uint4_t*)((char*)qlds + ((rr * 32 + (b ^ (rr & 7))) << 4)) = qv[i];
    }

    // ---- stage x group 0 into buf0 (validated fragment order/swizzle) ----
    const int wchunk = swz((xo & 3) * 64 + (xo >> 2) * 16 + xr);
    half8_t* xb = (half8_t*)xstage;
    {
        half8_t st;
        st[0] = (_Float16)pxa[0]; st[1] = (_Float16)pxb[0];
        st[2] = (_Float16)pxa[1]; st[3] = (_Float16)pxb[1];
        st[4] = (_Float16)pxa[2]; st[5] = (_Float16)pxb[2];
        st[6] = (_Float16)pxa[3]; st[7] = (_Float16)pxb[3];
        xb[wchunk] = st;
    }
    // prefetch x group 1
    pxa = *(const float4_t*)(xbase + GROUP_SZ);
    pxb = *(const float4_t*)(xbase + GROUP_SZ + 4);

    int rfc[4];
    #pragma unroll
    for (int j = 0; j < 4; ++j)
        rfc[j] = swz(j * 64 + lane);
    const int qrr = w * 16 + nlo;  // this lane's qlds row

    float4_t outacc = {0.f, 0.f, 0.f, 0.f};
    float pg[GPB];

    #pragma unroll
    for (int g = 0; g < GPB; ++g) {
        // barrier: (a) makes buf[g&1] writes visible, (b) guarantees the
        // previous group's reads of buf[(g+1)&1] are done before overwrite
        __syncthreads();

        if (g + 1 < GPB) {
            half8_t st;
            st[0] = (_Float16)pxa[0]; st[1] = (_Float16)pxb[0];
            st[2] = (_Float16)pxa[1]; st[3] = (_Float16)pxb[1];
            st[4] = (_Float16)pxa[2]; st[5] = (_Float16)pxb[2];
            st[6] = (_Float16)pxa[3]; st[7] = (_Float16)pxb[3];
            xb[(((g + 1) & 1) << 8) + wchunk] = st;
        }
        if (g + 2 < GPB) {
            pxa = *(const float4_t*)(xbase + (g + 2) * GROUP_SZ);
            pxb = *(const float4_t*)(xbase + (g + 2) * GROUP_SZ + 4);
        }

        // B: one ds_read_b128 = 4 packed int32 (k-chunk quad*32..+32)
        const uint4_t bw = *(const uint4_t*)((const char*)qlds
            + ((qrr * 32 + ((g * 4 + quad) ^ (qrr & 7))) << 4));

        // A fragments from the shared staged buffer
        half8_t af[4];
        #pragma unroll
        for (int j = 0; j < 4; ++j)
            af[j] = xb[((g & 1) << 8) + rfc[j]];

        float4_t ge = {0.f, 0.f, 0.f, 0.f};
        float4_t go = {0.f, 0.f, 0.f, 0.f};
        float p0 = 0.f, p1 = 0.f;
        #pragma unroll
        for (int j = 0; j < 4; ++j) {
            const half2_t one = {(_Float16)1.f, (_Float16)1.f};
            half2_t q0 = {af[j][0], af[j][1]}, q1 = {af[j][2], af[j][3]};
            half2_t q2 = {af[j][4], af[j][5]}, q3 = {af[j][6], af[j][7]};
#if __has_builtin(__builtin_amdgcn_fdot2)
            if (j < 2) {
                p0 = __builtin_amdgcn_fdot2(q0, one, p0, false);
                p0 = __builtin_amdgcn_fdot2(q1, one, p0, false);
                p0 = __builtin_amdgcn_fdot2(q2, one, p0, false);
                p0 = __builtin_amdgcn_fdot2(q3, one, p0, false);
            } else {
                p1 = __builtin_amdgcn_fdot2(q0, one, p1, false);
                p1 = __builtin_amdgcn_fdot2(q1, one, p1, false);
                p1 = __builtin_amdgcn_fdot2(q2, one, p1, false);
                p1 = __builtin_amdgcn_fdot2(q3, one, p1, false);
            }
#else
            float acc = (float)af[j][0] + (float)af[j][1] + (float)af[j][2]
                      + (float)af[j][3] + (float)af[j][4] + (float)af[j][5]
                      + (float)af[j][6] + (float)af[j][7];
            if (j < 2) p0 += acc; else p1 += acc;
#endif
            const uint32_t d = bw[j];
            uint4_t bb;
            bb.x = ( d         & 0x000F000Fu) | 0x64006400u;  // nibbles (0,4)
            bb.y = ((d >> 4)   & 0x000F000Fu) | 0x64006400u;  // (1,5)
            bb.z = ((d >> 8)   & 0x000F000Fu) | 0x64006400u;  // (2,6)
            bb.w = ((d >> 12)  & 0x000F000Fu) | 0x64006400u;  // (3,7)
            if ((j & 1) == 0)
                ge = __builtin_amdgcn_mfma_f32_16x16x32_f16(
                         af[j], __builtin_bit_cast(half8_t, bb), ge, 0, 0, 0);
            else
                go = __builtin_amdgcn_mfma_f32_16x16x32_f16(
                         af[j], __builtin_bit_cast(half8_t, bb), go, 0, 0, 0);
        }
        pg[g] = p0 + p1;
        #pragma unroll
        for (int r = 0; r < 4; ++r)
            outacc[r] = fmaf(sA[g], ge[r] + go[r], outacc[r]);
    }

    // ---- epilogue: deferred zero-point correction (shuffles pipeline) ----
    #pragma unroll
    for (int g = 0; g < GPB; ++g) {
        pg[g] += __shfl_xor(pg[g], 16, 64);
        pg[g] += __shfl_xor(pg[g], 32, 64);
    }
    #pragma unroll
    for (int r = 0; r < 4; ++r) {
        float acc = outacc[r];
        #pragma unroll
        for (int g = 0; g < GPB; ++g)
            acc = fmaf(cA[g], __shfl(pg[g], quad * 4 + r, 64), acc);
        // split-k partial: D-row m = quad*4 + r, col n
        atomicAdd(out + (size_t)(quad * 4 + r) * NN + n, acc);
    }
}

// ---------------------------------------------------------------------------
extern "C" void kernel_launch(void* const* d_in, const int* in_sizes, int n_in,
                              void* d_out, int out_size, void* d_ws, size_t ws_size,
                              hipStream_t stream) {
    const float* x      = (const float*)d_in[0];   // [16, 8192]
    const int*   qw     = (const int*)d_in[1];     // [8192, 1024]
    const float* scales = (const float*)d_in[2];   // [64, 8192]
    const float* zeros  = (const float*)d_in[3];   // [64, 8192]
    const float* bias   = (const float*)d_in[4];   // [8192]
    float* out = (float*)d_out;                    // [16, 8192] fp32
    (void)d_ws; (void)ws_size; (void)in_sizes; (void)n_in;

    wq_init<<<MM * NN / (256 * 4), 256, 0, stream>>>(bias, out);
    wq_main<<<NT * KQN, 256, 0, stream>>>(x, qw, scales, zeros, out);
}